// Round 4
// baseline (1927.596 us; speedup 1.0000x reference)
//
#include <hip/hip_runtime.h>
#include <hip/hip_bf16.h>

#define NN 50000
#define EE 800000

typedef unsigned short u16;
typedef unsigned int u32;

__device__ __forceinline__ float bfu2f(u16 b) { return __builtin_bit_cast(float, ((u32)b) << 16); }
__device__ __forceinline__ float lo16(u32 d) { return __builtin_bit_cast(float, d << 16); }
__device__ __forceinline__ float hi16(u32 d) { return __builtin_bit_cast(float, d & 0xffff0000u); }
__device__ __forceinline__ u16 f2bfu(float f) {
    u32 u = __builtin_bit_cast(u32, f);
    u32 r = (u + 0x7fffu + ((u >> 16) & 1u)) >> 16;
    return (u16)r;
}

// ---------------------------------------------------------------------------
// K1: per-node prep. wave-per-node, half-wave scalar / half-wave vector.
//   h_s  = h_s0 @ W1_s * inv_m             -> hs_out (bf16, ws)
//   h_v  = einsum(num,uw->nwm) * inv_m     -> hv_out (bf16, ws)
//   sc_s/sc_v -> out (f32; k3 adds agg terms on top)
// LDS: Wsc_s/Wsc_v as bf16 [u][w][v(16)] with 2-bit XOR chunk swizzle (64KB).
// ---------------------------------------------------------------------------
__global__ __launch_bounds__(1024) void k1_node(
    const float* __restrict__ x, const float* __restrict__ h,
    const float* __restrict__ W1s, const float* __restrict__ W1v,
    const float* __restrict__ Wscs, const float* __restrict__ Wscv,
    u16* __restrict__ hs_out, u16* __restrict__ hv_out, float* __restrict__ out)
{
    __shared__ __align__(16) u16 sWs[32 * 32 * 16];
    __shared__ __align__(16) u16 sWv[32 * 32 * 16];
    const int tid = threadIdx.x;
    for (int idx = tid; idx < 16384; idx += 1024) {
        int u = idx >> 9, v = (idx >> 5) & 15, w = idx & 31;
        int a = (u * 32 + w) * 16 + (((v >> 2) ^ ((w >> 2) & 3)) << 2) + (v & 3);
        sWs[a] = f2bfu(Wscs[idx]);
        sWv[a] = f2bfu(Wscv[idx]);
    }
    __syncthreads();

    const int wv = tid >> 6, lane = tid & 63;
    const int half = lane >> 5, w = lane & 31;
    const int sw = (w >> 2) & 3;
    const u16* __restrict__ sW = half ? sWv : sWs;
    const float* __restrict__ W1 = half ? W1v : W1s;
    const float inv_sc = 0.04419417382415922f;  // 1/sqrt(512)
    const float inv_m = 0.17677669529663687f;   // 1/sqrt(32)

    for (int n = blockIdx.x * 16 + wv; n < NN; n += gridDim.x * 16) {
        const float* __restrict__ xrow = x + (size_t)n * 16;
        const float* __restrict__ hrow = h + (size_t)n * 128;
        float xr[16];
#pragma unroll
        for (int v = 0; v < 16; v++) xr[v] = xrow[v];
        float a0 = 0.f, a1 = 0.f, a2 = 0.f, b0 = 0.f, b1 = 0.f, b2 = 0.f;
#pragma unroll 2
        for (int u = 0; u < 32; u++) {
            int off = half ? (32 + u * 3) : u;
            float h0 = hrow[off];
            float h1 = half ? hrow[off + 1] : 0.f;
            float h2 = half ? hrow[off + 2] : 0.f;
            float w1 = W1[u * 32 + w];
            const u16* rowp = sW + (u * 32 + w) * 16;
            float bb = 0.f;
#pragma unroll
            for (int c = 0; c < 4; c++) {
                uint2 q = *reinterpret_cast<const uint2*>(rowp + ((c ^ sw) << 2));
                bb += xr[4 * c + 0] * lo16(q.x) + xr[4 * c + 1] * hi16(q.x)
                    + xr[4 * c + 2] * lo16(q.y) + xr[4 * c + 3] * hi16(q.y);
            }
            a0 += h0 * bb; a1 += h1 * bb; a2 += h2 * bb;
            b0 += h0 * w1; b1 += h1 * w1; b2 += h2 * w1;
        }
        if (half == 0) {
            hs_out[(size_t)n * 32 + w] = f2bfu(b0 * inv_m);
            out[(size_t)n * 128 + w] = a0 * inv_sc;
        } else {
            size_t hb = ((size_t)n * 32 + w) * 3;
            hv_out[hb + 0] = f2bfu(b0 * inv_m);
            hv_out[hb + 1] = f2bfu(b1 * inv_m);
            hv_out[hb + 2] = f2bfu(b2 * inv_m);
            size_t ob = (size_t)n * 128 + 32 + (size_t)w * 3;
            out[ob + 0] = a0 * inv_sc;
            out[ob + 1] = a1 * inv_sc;
            out[ob + 2] = a2 * inv_sc;
        }
    }
}

// ---------------------------------------------------------------------------
// K2: per-edge MLP + tensor-product message + atomic scatter. wave-per-edge.
// agg_s[dst][c]: c<32 -> sA[u=c], c>=32 -> sD[u=c-32]
// agg_v[dst][c][m]: c<32 -> vB, c>=32 -> vC   (c == lane)
// ---------------------------------------------------------------------------
__global__ __launch_bounds__(256) void k2_edge(
    const float* __restrict__ emb, const float* __restrict__ esh,
    const int* __restrict__ eidx,
    const float* __restrict__ fc1, const float* __restrict__ fc2,
    const u16* __restrict__ hs, const u16* __restrict__ hv,
    float* __restrict__ aggs, float* __restrict__ aggv)
{
    __shared__ float sfc1[64];
    __shared__ float sfc2[1024];
    const int tid = threadIdx.x;
    if (tid < 64) sfc1[tid] = fc1[tid];
    for (int i = tid; i < 1024; i += 256) sfc2[i] = fc2[i];
    __syncthreads();

    const int lane = tid & 63;
    const int wvu = tid >> 6;
    const int e = blockIdx.x * 4 + wvu;
    const int dst = eidx[e];
    const int src = eidx[EE + e];

    const float invb = 0.3535533905932738f;  // 1/sqrt(8) (= 1/sqrt(HID) too)
    const int k8 = lane & 7;
    float t = 0.f;
#pragma unroll
    for (int j = 0; j < 8; j++) t += emb[(size_t)e * 8 + j] * sfc1[j * 8 + k8];
    t *= invb;
    float zk = t / (1.f + __expf(-t));
    float z[8];
#pragma unroll
    for (int j = 0; j < 8; j++) z[j] = __shfl(zk, j);

    const int u = lane & 31;
    const int cs = (lane < 32) ? lane : (96 + u);       // wA / wD index
    const int cv = (lane < 32) ? (32 + u) : (64 + u);   // wB / wC index
    float ws_ = 0.f, wv_ = 0.f;
#pragma unroll
    for (int j = 0; j < 8; j++) {
        ws_ += z[j] * sfc2[j * 128 + cs];
        wv_ += z[j] * sfc2[j * 128 + cv];
    }
    ws_ *= invb; wv_ *= invb;

    float sh0 = esh[(size_t)e * 4 + 0];
    float s1x = esh[(size_t)e * 4 + 1];
    float s1y = esh[(size_t)e * 4 + 2];
    float s1z = esh[(size_t)e * 4 + 3];

    float sval, v0, v1, v2;
    if (lane < 32) {
        float hsv = bfu2f(hs[(size_t)src * 32 + u]);
        sval = hsv * sh0 * ws_;
        v0 = hsv * s1x * wv_; v1 = hsv * s1y * wv_; v2 = hsv * s1z * wv_;
    } else {
        size_t hb = ((size_t)src * 32 + u) * 3;
        float h0 = bfu2f(hv[hb]), h1 = bfu2f(hv[hb + 1]), h2 = bfu2f(hv[hb + 2]);
        sval = (h0 * s1x + h1 * s1y + h2 * s1z) * ws_ * 0.5773502691896258f;  // 1/sqrt(3)
        v0 = h0 * sh0 * wv_; v1 = h1 * sh0 * wv_; v2 = h2 * sh0 * wv_;
    }
    atomicAdd(aggs + (size_t)dst * 64 + lane, sval);
    float* vp = aggv + ((size_t)dst * 64 + lane) * 3;
    atomicAdd(vp + 0, v0);
    atomicAdd(vp + 1, v1);
    atomicAdd(vp + 2, v2);
}

// ---------------------------------------------------------------------------
// K3: out = agg @ W2 * inv_n*inv2 + sc (sc already in out, f32). wave-per-node.
// ---------------------------------------------------------------------------
__global__ __launch_bounds__(256) void k3_final(
    const float* __restrict__ aggs, const float* __restrict__ aggv,
    const float* __restrict__ W2s, const float* __restrict__ W2v,
    float* __restrict__ out)
{
    __shared__ float sW2s[2048];
    __shared__ float sW2v[2048];
    const int tid = threadIdx.x;
    for (int i = tid; i < 2048; i += 256) {
        sW2s[i] = W2s[i];
        sW2v[i] = W2v[i];
    }
    __syncthreads();

    const int wv = tid >> 6, lane = tid & 63;
    const float sc2 = 0.03125f;  // inv_n * inv2 = 0.25 * 0.125
    for (int n = blockIdx.x * 4 + wv; n < NN; n += gridDim.x * 4) {
        if (lane < 32) {
            const int w = lane;
            float acc = 0.f;
            const float* ap = aggs + (size_t)n * 64;
#pragma unroll 8
            for (int u = 0; u < 64; u++) acc += ap[u] * sW2s[u * 32 + w];
            size_t o = (size_t)n * 128 + w;
            out[o] = acc * sc2 + out[o];
        } else {
            const int w = lane - 32;
            float a0 = 0.f, a1 = 0.f, a2 = 0.f;
            const float* vp = aggv + (size_t)n * 192;
#pragma unroll 4
            for (int u = 0; u < 64; u++) {
                float wt = sW2v[u * 32 + w];
                a0 += vp[u * 3 + 0] * wt;
                a1 += vp[u * 3 + 1] * wt;
                a2 += vp[u * 3 + 2] * wt;
            }
            size_t o = (size_t)n * 128 + 32 + (size_t)w * 3;
            out[o + 0] = a0 * sc2 + out[o + 0];
            out[o + 1] = a1 * sc2 + out[o + 1];
            out[o + 2] = a2 * sc2 + out[o + 2];
        }
    }
}

extern "C" void kernel_launch(void* const* d_in, const int* in_sizes, int n_in,
                              void* d_out, int out_size, void* d_ws, size_t ws_size,
                              hipStream_t stream) {
    const float* x    = (const float*)d_in[0];
    const float* h    = (const float*)d_in[1];
    const float* emb  = (const float*)d_in[2];
    const float* esh  = (const float*)d_in[3];
    const int*   eidx = (const int*)d_in[4];
    const float* W1s  = (const float*)d_in[5];
    const float* W1v  = (const float*)d_in[6];
    const float* fc1  = (const float*)d_in[7];
    const float* fc2  = (const float*)d_in[8];
    const float* Wscs = (const float*)d_in[9];
    const float* Wscv = (const float*)d_in[10];
    const float* W2s  = (const float*)d_in[11];
    const float* W2v  = (const float*)d_in[12];
    float* out = (float*)d_out;

    // ws layout: aggs f32[N*64] | aggv f32[N*192] | hs bf16[N*32] | hv bf16[N*96]
    float* aggs = (float*)d_ws;
    float* aggv = aggs + (size_t)NN * 64;
    u16* hs = (u16*)(aggv + (size_t)NN * 192);
    u16* hv = hs + (size_t)NN * 32;

    hipMemsetAsync(d_ws, 0, (size_t)NN * 256 * 4, stream);
    k1_node<<<512, 1024, 0, stream>>>(x, h, W1s, W1v, Wscs, Wscv, hs, hv, out);
    k2_edge<<<EE / 4, 256, 0, stream>>>(emb, esh, eidx, fc1, fc2, hs, hv, aggs, aggv);
    k3_final<<<12500, 256, 0, stream>>>(aggs, aggv, W2s, W2v, out);
}

// Round 5
// 604.610 us; speedup vs baseline: 3.1882x; 3.1882x over previous
//
#include <hip/hip_runtime.h>
#include <hip/hip_bf16.h>

#define NN 50000
#define EE 800000

typedef unsigned short u16;
typedef unsigned int u32;

__device__ __forceinline__ float bfu2f(u16 b) { return __builtin_bit_cast(float, ((u32)b) << 16); }
__device__ __forceinline__ float lo16(u32 d) { return __builtin_bit_cast(float, d << 16); }
__device__ __forceinline__ float hi16(u32 d) { return __builtin_bit_cast(float, d & 0xffff0000u); }
__device__ __forceinline__ u16 f2bfu(float f) {
    u32 u = __builtin_bit_cast(u32, f);
    u32 r = (u + 0x7fffu + ((u >> 16) & 1u)) >> 16;
    return (u16)r;
}

// ---------------------------------------------------------------------------
// K1: per-node prep (unchanged from passing round).
// ---------------------------------------------------------------------------
__global__ __launch_bounds__(1024) void k1_node(
    const float* __restrict__ x, const float* __restrict__ h,
    const float* __restrict__ W1s, const float* __restrict__ W1v,
    const float* __restrict__ Wscs, const float* __restrict__ Wscv,
    u16* __restrict__ hs_out, u16* __restrict__ hv_out, float* __restrict__ out)
{
    __shared__ __align__(16) u16 sWs[32 * 32 * 16];
    __shared__ __align__(16) u16 sWv[32 * 32 * 16];
    const int tid = threadIdx.x;
    for (int idx = tid; idx < 16384; idx += 1024) {
        int u = idx >> 9, v = (idx >> 5) & 15, w = idx & 31;
        int a = (u * 32 + w) * 16 + (((v >> 2) ^ ((w >> 2) & 3)) << 2) + (v & 3);
        sWs[a] = f2bfu(Wscs[idx]);
        sWv[a] = f2bfu(Wscv[idx]);
    }
    __syncthreads();

    const int wv = tid >> 6, lane = tid & 63;
    const int half = lane >> 5, w = lane & 31;
    const int sw = (w >> 2) & 3;
    const u16* __restrict__ sW = half ? sWv : sWs;
    const float* __restrict__ W1 = half ? W1v : W1s;
    const float inv_sc = 0.04419417382415922f;  // 1/sqrt(512)
    const float inv_m = 0.17677669529663687f;   // 1/sqrt(32)

    for (int n = blockIdx.x * 16 + wv; n < NN; n += gridDim.x * 16) {
        const float* __restrict__ xrow = x + (size_t)n * 16;
        const float* __restrict__ hrow = h + (size_t)n * 128;
        float xr[16];
#pragma unroll
        for (int v = 0; v < 16; v++) xr[v] = xrow[v];
        float a0 = 0.f, a1 = 0.f, a2 = 0.f, b0 = 0.f, b1 = 0.f, b2 = 0.f;
#pragma unroll 2
        for (int u = 0; u < 32; u++) {
            int off = half ? (32 + u * 3) : u;
            float h0 = hrow[off];
            float h1 = half ? hrow[off + 1] : 0.f;
            float h2 = half ? hrow[off + 2] : 0.f;
            float w1 = W1[u * 32 + w];
            const u16* rowp = sW + (u * 32 + w) * 16;
            float bb = 0.f;
#pragma unroll
            for (int c = 0; c < 4; c++) {
                uint2 q = *reinterpret_cast<const uint2*>(rowp + ((c ^ sw) << 2));
                bb += xr[4 * c + 0] * lo16(q.x) + xr[4 * c + 1] * hi16(q.x)
                    + xr[4 * c + 2] * lo16(q.y) + xr[4 * c + 3] * hi16(q.y);
            }
            a0 += h0 * bb; a1 += h1 * bb; a2 += h2 * bb;
            b0 += h0 * w1; b1 += h1 * w1; b2 += h2 * w1;
        }
        if (half == 0) {
            hs_out[(size_t)n * 32 + w] = f2bfu(b0 * inv_m);
            out[(size_t)n * 128 + w] = a0 * inv_sc;
        } else {
            size_t hb = ((size_t)n * 32 + w) * 3;
            hv_out[hb + 0] = f2bfu(b0 * inv_m);
            hv_out[hb + 1] = f2bfu(b1 * inv_m);
            hv_out[hb + 2] = f2bfu(b2 * inv_m);
            size_t ob = (size_t)n * 128 + 32 + (size_t)w * 3;
            out[ob + 0] = a0 * inv_sc;
            out[ob + 1] = a1 * inv_sc;
            out[ob + 2] = a2 * inv_sc;
        }
    }
}

// ---------------------------------------------------------------------------
// CSR build: histogram -> scan -> scatter (int atomics on L2-resident arrays)
// ---------------------------------------------------------------------------
__global__ __launch_bounds__(256) void k_hist(const int* __restrict__ eidx, int* __restrict__ deg) {
    int e = blockIdx.x * 256 + threadIdx.x;
    if (e < EE) atomicAdd(&deg[eidx[e]], 1);
}

__global__ __launch_bounds__(1024) void k_scan(const int* __restrict__ deg, int* __restrict__ row_ptr) {
    __shared__ int part[1024];
    const int t = threadIdx.x;
    const int base = t * 49;  // 1024*49 = 50176 >= 50000
    int s = 0;
#pragma unroll 7
    for (int i = 0; i < 49; i++) { int idx = base + i; if (idx < NN) s += deg[idx]; }
    part[t] = s;
    __syncthreads();
    for (int off = 1; off < 1024; off <<= 1) {
        int v = (t >= off) ? part[t - off] : 0;
        __syncthreads();
        part[t] += v;
        __syncthreads();
    }
    int run = (t > 0) ? part[t - 1] : 0;
    for (int i = 0; i < 49; i++) {
        int idx = base + i;
        if (idx < NN) { row_ptr[idx] = run; run += deg[idx]; }
    }
    if (t == 1023) row_ptr[NN] = run;  // == EE
}

__global__ __launch_bounds__(256) void k_scatter(
    const int* __restrict__ eidx, const int* __restrict__ row_ptr,
    int* __restrict__ cursor, int* __restrict__ edge_ids) {
    int e = blockIdx.x * 256 + threadIdx.x;
    if (e < EE) {
        int d = eidx[e];
        int p = atomicAdd(&cursor[d], 1);
        edge_ids[row_ptr[d] + p] = e;
    }
}

// ---------------------------------------------------------------------------
// K2b: fused gather + aggregate + output transform. One wave per dst node.
// Lane c owns mid-channel c: c<32 -> {sA,vB}[u=c], c>=32 -> {sD,vC}[u=c-32].
// Epilogue: per-wave LDS transpose + agg@W2*sc2 added onto sc (already in out).
// ---------------------------------------------------------------------------
__global__ __launch_bounds__(256) void k2b_gather(
    const float* __restrict__ emb, const float* __restrict__ esh,
    const int* __restrict__ eidx,
    const float* __restrict__ fc1, const float* __restrict__ fc2,
    const u16* __restrict__ hs, const u16* __restrict__ hv,
    const int* __restrict__ row_ptr, const int* __restrict__ edge_ids,
    const float* __restrict__ W2s, const float* __restrict__ W2v,
    float* __restrict__ out)
{
    __shared__ float sfc1[64];
    __shared__ float sfc2[1024];
    __shared__ float sW2s[2048];
    __shared__ float sW2v[2048];
    __shared__ float sred[4][256];
    const int tid = threadIdx.x;
    if (tid < 64) sfc1[tid] = fc1[tid];
    for (int i = tid; i < 1024; i += 256) sfc2[i] = fc2[i];
    for (int i = tid; i < 2048; i += 256) { sW2s[i] = W2s[i]; sW2v[i] = W2v[i]; }
    __syncthreads();

    const int wv = tid >> 6, lane = tid & 63;
    const int n = blockIdx.x * 4 + wv;  // grid exact: 12500*4 == NN
    const int beg = row_ptr[n], end = row_ptr[n + 1];

    const float invb = 0.3535533905932738f;   // 1/sqrt(8)
    const float inv3 = 0.5773502691896258f;   // 1/sqrt(3)
    const int u = lane & 31;
    const int k8 = lane & 7;
    const int cs = (lane < 32) ? lane : (96 + u);      // wA / wD col
    const int cv = (lane < 32) ? (32 + u) : (64 + u);  // wB / wC col

    float acc_s = 0.f, av0 = 0.f, av1 = 0.f, av2 = 0.f;

    for (int cb = beg; cb < end; cb += 64) {
        const int cnt = min(64, end - cb);
        int eidl = (lane < cnt) ? edge_ids[cb + lane] : 0;
        int srcl = (lane < cnt) ? eidx[EE + eidl] : 0;
        for (int i = 0; i < cnt; i++) {
            const int e = __shfl(eidl, i);
            const int src = __shfl(srcl, i);
            // tiny MLP: z = silu(emb@fc1*invb), w = z@fc2*invb
            float t = 0.f;
#pragma unroll
            for (int j = 0; j < 8; j++) t += emb[(size_t)e * 8 + j] * sfc1[j * 8 + k8];
            t *= invb;
            float zk = t / (1.f + __expf(-t));
            float ws_ = 0.f, wv_ = 0.f;
#pragma unroll
            for (int j = 0; j < 8; j++) {
                float zj = __shfl(zk, j);
                ws_ += zj * sfc2[j * 128 + cs];
                wv_ += zj * sfc2[j * 128 + cv];
            }
            ws_ *= invb; wv_ *= invb;

            float sh0 = esh[(size_t)e * 4 + 0];
            float s1x = esh[(size_t)e * 4 + 1];
            float s1y = esh[(size_t)e * 4 + 2];
            float s1z = esh[(size_t)e * 4 + 3];

            if (lane < 32) {
                float hsv = bfu2f(hs[(size_t)src * 32 + u]);
                acc_s += hsv * sh0 * ws_;
                av0 += hsv * s1x * wv_; av1 += hsv * s1y * wv_; av2 += hsv * s1z * wv_;
            } else {
                size_t hb = ((size_t)src * 32 + u) * 3;
                float h0 = bfu2f(hv[hb]), h1 = bfu2f(hv[hb + 1]), h2 = bfu2f(hv[hb + 2]);
                acc_s += (h0 * s1x + h1 * s1y + h2 * s1z) * ws_ * inv3;
                av0 += h0 * sh0 * wv_; av1 += h1 * sh0 * wv_; av2 += h2 * sh0 * wv_;
            }
        }
    }

    // per-wave cross-lane transpose via LDS (each wave uses its own region)
    float* red = sred[wv];
    red[lane] = acc_s;
    red[64 + lane * 3 + 0] = av0;
    red[64 + lane * 3 + 1] = av1;
    red[64 + lane * 3 + 2] = av2;
    __syncthreads();  // all 4 waves execute this exactly once -> convergent

    const float sc2 = 0.03125f;  // inv_n * inv2 = 0.25 * 0.125
    if (lane < 32) {
        float acc = 0.f;
#pragma unroll 8
        for (int c = 0; c < 64; c++) acc += red[c] * sW2s[c * 32 + lane];
        size_t o = (size_t)n * 128 + lane;
        out[o] += acc * sc2;
    } else {
        const int w = lane - 32;
        float a0 = 0.f, a1 = 0.f, a2 = 0.f;
#pragma unroll 4
        for (int c = 0; c < 64; c++) {
            float wt = sW2v[c * 32 + w];
            a0 += red[64 + c * 3 + 0] * wt;
            a1 += red[64 + c * 3 + 1] * wt;
            a2 += red[64 + c * 3 + 2] * wt;
        }
        size_t o = (size_t)n * 128 + 32 + (size_t)w * 3;
        out[o + 0] += a0 * sc2;
        out[o + 1] += a1 * sc2;
        out[o + 2] += a2 * sc2;
    }
}

extern "C" void kernel_launch(void* const* d_in, const int* in_sizes, int n_in,
                              void* d_out, int out_size, void* d_ws, size_t ws_size,
                              hipStream_t stream) {
    const float* x    = (const float*)d_in[0];
    const float* h    = (const float*)d_in[1];
    const float* emb  = (const float*)d_in[2];
    const float* esh  = (const float*)d_in[3];
    const int*   eidx = (const int*)d_in[4];
    const float* W1s  = (const float*)d_in[5];
    const float* W1v  = (const float*)d_in[6];
    const float* fc1  = (const float*)d_in[7];
    const float* fc2  = (const float*)d_in[8];
    const float* Wscs = (const float*)d_in[9];
    const float* Wscv = (const float*)d_in[10];
    const float* W2s  = (const float*)d_in[11];
    const float* W2v  = (const float*)d_in[12];
    float* out = (float*)d_out;

    // ws layout: deg[50000] | row_ptr[50001] | cursor[50000] | edge_ids[800000]
    //            | hs bf16[N*32] | hv bf16[N*96]   (~16.6 MB total)
    int* deg      = (int*)d_ws;
    int* row_ptr  = deg + NN;
    int* cursor   = row_ptr + (NN + 1);
    int* edge_ids = cursor + NN;
    u16* hs = (u16*)(edge_ids + EE);
    u16* hv = hs + (size_t)NN * 32;

    // zero deg + cursor (row_ptr in between gets overwritten by scan)
    hipMemsetAsync(d_ws, 0, (size_t)(NN + NN + 1 + NN) * 4, stream);
    k1_node<<<512, 1024, 0, stream>>>(x, h, W1s, W1v, Wscs, Wscv, hs, hv, out);
    k_hist<<<(EE + 255) / 256, 256, 0, stream>>>(eidx, deg);
    k_scan<<<1, 1024, 0, stream>>>(deg, row_ptr);
    k_scatter<<<(EE + 255) / 256, 256, 0, stream>>>(eidx, row_ptr, cursor, edge_ids);
    k2b_gather<<<NN / 4, 256, 0, stream>>>(emb, esh, eidx, fc1, fc2, hs, hv,
                                           row_ptr, edge_ids, W2s, W2v, out);
}

// Round 7
// 470.347 us; speedup vs baseline: 4.0982x; 1.2855x over previous
//
#include <hip/hip_runtime.h>
#include <hip/hip_bf16.h>

#define NN 50000
#define EE 800000

typedef unsigned short u16;
typedef unsigned int u32;

__device__ __forceinline__ float bfu2f(u16 b) { return __builtin_bit_cast(float, ((u32)b) << 16); }
__device__ __forceinline__ float lo16(u32 d) { return __builtin_bit_cast(float, d << 16); }
__device__ __forceinline__ float hi16(u32 d) { return __builtin_bit_cast(float, d & 0xffff0000u); }
__device__ __forceinline__ u16 f2bfu(float f) {
    u32 u = __builtin_bit_cast(u32, f);
    u32 r = (u + 0x7fffu + ((u >> 16) & 1u)) >> 16;
    return (u16)r;
}

// ---------------------------------------------------------------------------
// K1: per-node prep. hs/hv merged: hsv[node] = 128 u16 = [32 hs][96 hv].
// ---------------------------------------------------------------------------
__global__ __launch_bounds__(1024) void k1_node(
    const float* __restrict__ x, const float* __restrict__ h,
    const float* __restrict__ W1s, const float* __restrict__ W1v,
    const float* __restrict__ Wscs, const float* __restrict__ Wscv,
    u16* __restrict__ hsv, float* __restrict__ out)
{
    __shared__ __align__(16) u16 sWs[32 * 32 * 16];
    __shared__ __align__(16) u16 sWv[32 * 32 * 16];
    const int tid = threadIdx.x;
    for (int idx = tid; idx < 16384; idx += 1024) {
        int u = idx >> 9, v = (idx >> 5) & 15, w = idx & 31;
        int a = (u * 32 + w) * 16 + (((v >> 2) ^ ((w >> 2) & 3)) << 2) + (v & 3);
        sWs[a] = f2bfu(Wscs[idx]);
        sWv[a] = f2bfu(Wscv[idx]);
    }
    __syncthreads();

    const int wv = tid >> 6, lane = tid & 63;
    const int half = lane >> 5, w = lane & 31;
    const int sw = (w >> 2) & 3;
    const u16* __restrict__ sW = half ? sWv : sWs;
    const float* __restrict__ W1 = half ? W1v : W1s;
    const float inv_sc = 0.04419417382415922f;  // 1/sqrt(512)
    const float inv_m = 0.17677669529663687f;   // 1/sqrt(32)

    for (int n = blockIdx.x * 16 + wv; n < NN; n += gridDim.x * 16) {
        const float* __restrict__ xrow = x + (size_t)n * 16;
        const float* __restrict__ hrow = h + (size_t)n * 128;
        float xr[16];
#pragma unroll
        for (int v = 0; v < 16; v++) xr[v] = xrow[v];
        float a0 = 0.f, a1 = 0.f, a2 = 0.f, b0 = 0.f, b1 = 0.f, b2 = 0.f;
#pragma unroll 2
        for (int u = 0; u < 32; u++) {
            int off = half ? (32 + u * 3) : u;
            float h0 = hrow[off];
            float h1 = half ? hrow[off + 1] : 0.f;
            float h2 = half ? hrow[off + 2] : 0.f;
            float w1 = W1[u * 32 + w];
            const u16* rowp = sW + (u * 32 + w) * 16;
            float bb = 0.f;
#pragma unroll
            for (int c = 0; c < 4; c++) {
                uint2 q = *reinterpret_cast<const uint2*>(rowp + ((c ^ sw) << 2));
                bb += xr[4 * c + 0] * lo16(q.x) + xr[4 * c + 1] * hi16(q.x)
                    + xr[4 * c + 2] * lo16(q.y) + xr[4 * c + 3] * hi16(q.y);
            }
            a0 += h0 * bb; a1 += h1 * bb; a2 += h2 * bb;
            b0 += h0 * w1; b1 += h1 * w1; b2 += h2 * w1;
        }
        if (half == 0) {
            hsv[(size_t)n * 128 + w] = f2bfu(b0 * inv_m);
            out[(size_t)n * 128 + w] = a0 * inv_sc;
        } else {
            size_t hb = (size_t)n * 128 + 32 + (size_t)w * 3;
            hsv[hb + 0] = f2bfu(b0 * inv_m);
            hsv[hb + 1] = f2bfu(b1 * inv_m);
            hsv[hb + 2] = f2bfu(b2 * inv_m);
            size_t ob = (size_t)n * 128 + 32 + (size_t)w * 3;
            out[ob + 0] = a0 * inv_sc;
            out[ob + 1] = a1 * inv_sc;
            out[ob + 2] = a2 * inv_sc;
        }
    }
}

// ---------------------------------------------------------------------------
// CSR build: histogram -> scan. (scatter is fused into k2a)
// ---------------------------------------------------------------------------
__global__ __launch_bounds__(256) void k_hist(const int* __restrict__ eidx, int* __restrict__ deg) {
    int e = blockIdx.x * 256 + threadIdx.x;
    if (e < EE) atomicAdd(&deg[eidx[e]], 1);
}

__global__ __launch_bounds__(1024) void k_scan(const int* __restrict__ deg, int* __restrict__ row_ptr) {
    __shared__ int part[1024];
    const int t = threadIdx.x;
    const int base = t * 49;  // 1024*49 = 50176 >= 50000
    int s = 0;
#pragma unroll 7
    for (int i = 0; i < 49; i++) { int idx = base + i; if (idx < NN) s += deg[idx]; }
    part[t] = s;
    __syncthreads();
    for (int off = 1; off < 1024; off <<= 1) {
        int v = (t >= off) ? part[t - off] : 0;
        __syncthreads();
        part[t] += v;
        __syncthreads();
    }
    int run = (t > 0) ? part[t - 1] : 0;
    for (int i = 0; i < 49; i++) {
        int idx = base + i;
        if (idx < NN) { row_ptr[idx] = run; run += deg[idx]; }
    }
    if (t == 1023) row_ptr[NN] = run;  // == EE
}

// ---------------------------------------------------------------------------
// K2a: streaming per-edge MLP front-half (z = silu(emb@fc1/sqrt8)) + scatter
// of edata into CSR slot order. edata row (32B): z bf16x8 | esh bf16x4 | src.
// ---------------------------------------------------------------------------
__global__ __launch_bounds__(256) void k2a_edge(
    const float* __restrict__ emb, const float* __restrict__ esh,
    const int* __restrict__ eidx, const float* __restrict__ fc1,
    const int* __restrict__ row_ptr, int* __restrict__ cursor,
    u32* __restrict__ edata)
{
    __shared__ float sfc1[64];
    const int tid = threadIdx.x;
    if (tid < 64) sfc1[tid] = fc1[tid];
    __syncthreads();
    int e = blockIdx.x * 256 + tid;
    if (e >= EE) return;
    const float invb = 0.3535533905932738f;  // 1/sqrt(8)
    float4 ea = *(const float4*)(emb + (size_t)e * 8);
    float4 eb = *(const float4*)(emb + (size_t)e * 8 + 4);
    float em[8] = {ea.x, ea.y, ea.z, ea.w, eb.x, eb.y, eb.z, eb.w};
    float z[8];
#pragma unroll
    for (int k = 0; k < 8; k++) {
        float t = 0.f;
#pragma unroll
        for (int j = 0; j < 8; j++) t += em[j] * sfc1[j * 8 + k];
        t *= invb;
        z[k] = t / (1.f + __expf(-t));
    }
    float4 sh = *(const float4*)(esh + (size_t)e * 4);
    int dst = eidx[e], src = eidx[EE + e];
    int p = atomicAdd(&cursor[dst], 1);
    size_t slot = (size_t)row_ptr[dst] + p;
    u32* wp = edata + slot * 8;
    uint4 A, B;
    A.x = (u32)f2bfu(z[0]) | ((u32)f2bfu(z[1]) << 16);
    A.y = (u32)f2bfu(z[2]) | ((u32)f2bfu(z[3]) << 16);
    A.z = (u32)f2bfu(z[4]) | ((u32)f2bfu(z[5]) << 16);
    A.w = (u32)f2bfu(z[6]) | ((u32)f2bfu(z[7]) << 16);
    B.x = (u32)f2bfu(sh.x) | ((u32)f2bfu(sh.y) << 16);
    B.y = (u32)f2bfu(sh.z) | ((u32)f2bfu(sh.w) << 16);
    B.z = (u32)src;
    B.w = 0;
    *(uint4*)wp = A;
    *(uint4*)(wp + 4) = B;
}

// ---------------------------------------------------------------------------
// K2b: gather + aggregate + fused output transform. One wave per dst node.
// Per-lane fc2 columns hoisted to registers; edata read contiguously per row.
// ---------------------------------------------------------------------------
__device__ __forceinline__ void edge_body(
    const u32* __restrict__ r, const u16* __restrict__ hsv,
    const float* fcs, const float* fcv, int lane, int u, float inv3,
    float& acc_s, float& av0, float& av1, float& av2)
{
    uint4 A = *(const uint4*)r;
    uint4 B = *(const uint4*)(r + 4);
    float ws_ = lo16(A.x) * fcs[0] + hi16(A.x) * fcs[1] + lo16(A.y) * fcs[2] + hi16(A.y) * fcs[3]
              + lo16(A.z) * fcs[4] + hi16(A.z) * fcs[5] + lo16(A.w) * fcs[6] + hi16(A.w) * fcs[7];
    float wv_ = lo16(A.x) * fcv[0] + hi16(A.x) * fcv[1] + lo16(A.y) * fcv[2] + hi16(A.y) * fcv[3]
              + lo16(A.z) * fcv[4] + hi16(A.z) * fcv[5] + lo16(A.w) * fcv[6] + hi16(A.w) * fcv[7];
    float sh0 = lo16(B.x), s1x = hi16(B.x), s1y = lo16(B.y), s1z = hi16(B.y);
    const u16* hp = hsv + (size_t)(int)B.z * 128;
    if (lane < 32) {
        float hsvv = bfu2f(hp[u]);
        acc_s += hsvv * sh0 * ws_;
        av0 += hsvv * s1x * wv_; av1 += hsvv * s1y * wv_; av2 += hsvv * s1z * wv_;
    } else {
        const u16* q = hp + 32 + u * 3;
        float h0 = bfu2f(q[0]), h1 = bfu2f(q[1]), h2 = bfu2f(q[2]);
        acc_s += (h0 * s1x + h1 * s1y + h2 * s1z) * ws_ * inv3;
        av0 += h0 * sh0 * wv_; av1 += h1 * sh0 * wv_; av2 += h2 * sh0 * wv_;
    }
}

__global__ __launch_bounds__(256) void k2b_gather(
    const u32* __restrict__ edata, const float* __restrict__ fc2,
    const u16* __restrict__ hsv, const int* __restrict__ row_ptr,
    const float* __restrict__ W2s, const float* __restrict__ W2v,
    float* __restrict__ out)
{
    __shared__ float sW2s[2048];
    __shared__ float sW2v[2048];
    __shared__ float sred[4][256];
    const int tid = threadIdx.x;
    for (int i = tid; i < 2048; i += 256) { sW2s[i] = W2s[i]; sW2v[i] = W2v[i]; }

    const int wv = tid >> 6, lane = tid & 63;
    const int n = blockIdx.x * 4 + wv;  // grid exact: 12500*4 == NN
    const int beg = __builtin_amdgcn_readfirstlane(row_ptr[n]);
    const int end = __builtin_amdgcn_readfirstlane(row_ptr[n + 1]);

    const float invb = 0.3535533905932738f;   // 1/sqrt(8)
    const float inv3 = 0.5773502691896258f;   // 1/sqrt(3)
    const int u = lane & 31;
    const int cs = (lane < 32) ? lane : (96 + u);      // wA / wD col
    const int cv = (lane < 32) ? (32 + u) : (64 + u);  // wB / wC col
    float fcs[8], fcv[8];
#pragma unroll
    for (int j = 0; j < 8; j++) {
        fcs[j] = fc2[j * 128 + cs] * invb;
        fcv[j] = fc2[j * 128 + cv] * invb;
    }

    float a_s0 = 0.f, a00 = 0.f, a01 = 0.f, a02 = 0.f;
    float a_s1 = 0.f, a10 = 0.f, a11 = 0.f, a12 = 0.f;
    int s = beg;
    for (; s + 1 < end; s += 2) {
        edge_body(edata + (size_t)s * 8, hsv, fcs, fcv, lane, u, inv3, a_s0, a00, a01, a02);
        edge_body(edata + (size_t)(s + 1) * 8, hsv, fcs, fcv, lane, u, inv3, a_s1, a10, a11, a12);
    }
    if (s < end)
        edge_body(edata + (size_t)s * 8, hsv, fcs, fcv, lane, u, inv3, a_s0, a00, a01, a02);
    float acc_s = a_s0 + a_s1, av0 = a00 + a10, av1 = a01 + a11, av2 = a02 + a12;

    float* red = sred[wv];
    red[lane] = acc_s;
    red[64 + lane * 3 + 0] = av0;
    red[64 + lane * 3 + 1] = av1;
    red[64 + lane * 3 + 2] = av2;
    __syncthreads();  // also covers the W2 staging above

    const float sc2 = 0.03125f;  // inv_n * inv2 = 0.25 * 0.125
    if (lane < 32) {
        float acc = 0.f;
#pragma unroll 8
        for (int c = 0; c < 64; c++) acc += red[c] * sW2s[c * 32 + lane];
        size_t o = (size_t)n * 128 + lane;
        out[o] += acc * sc2;
    } else {
        const int w = lane - 32;
        float a0 = 0.f, a1 = 0.f, a2 = 0.f;
#pragma unroll 4
        for (int c = 0; c < 64; c++) {
            float wt = sW2v[c * 32 + w];
            a0 += red[64 + c * 3 + 0] * wt;
            a1 += red[64 + c * 3 + 1] * wt;
            a2 += red[64 + c * 3 + 2] * wt;
        }
        size_t o = (size_t)n * 128 + 32 + (size_t)w * 3;
        out[o + 0] += a0 * sc2;
        out[o + 1] += a1 * sc2;
        out[o + 2] += a2 * sc2;
    }
}

extern "C" void kernel_launch(void* const* d_in, const int* in_sizes, int n_in,
                              void* d_out, int out_size, void* d_ws, size_t ws_size,
                              hipStream_t stream) {
    const float* x    = (const float*)d_in[0];
    const float* h    = (const float*)d_in[1];
    const float* emb  = (const float*)d_in[2];
    const float* esh  = (const float*)d_in[3];
    const int*   eidx = (const int*)d_in[4];
    const float* W1s  = (const float*)d_in[5];
    const float* W1v  = (const float*)d_in[6];
    const float* fc1  = (const float*)d_in[7];
    const float* fc2  = (const float*)d_in[8];
    const float* Wscs = (const float*)d_in[9];
    const float* Wscv = (const float*)d_in[10];
    const float* W2s  = (const float*)d_in[11];
    const float* W2v  = (const float*)d_in[12];
    float* out = (float*)d_out;

    // ws layout: deg[NN] | row_ptr[NN+1] | cursor[NN] | edata u32[EE*8] (25.6MB)
    //            | hsv u16[NN*128] (12.8MB)
    int* deg      = (int*)d_ws;
    int* row_ptr  = deg + NN;
    int* cursor   = row_ptr + (NN + 1);
    u32* edata    = (u32*)(cursor + NN);
    u16* hsv      = (u16*)(edata + (size_t)EE * 8);

    hipMemsetAsync(d_ws, 0, (size_t)(NN + NN + 1 + NN) * 4, stream);
    k_hist<<<(EE + 255) / 256, 256, 0, stream>>>(eidx, deg);
    k_scan<<<1, 1024, 0, stream>>>(deg, row_ptr);
    k2a_edge<<<(EE + 255) / 256, 256, 0, stream>>>(emb, esh, eidx, fc1, row_ptr, cursor, edata);
    k1_node<<<512, 1024, 0, stream>>>(x, h, W1s, W1v, Wscs, Wscv, hsv, out);
    k2b_gather<<<NN / 4, 256, 0, stream>>>(edata, fc2, hsv, row_ptr, W2s, W2v, out);
}

// Round 8
// 372.386 us; speedup vs baseline: 5.1763x; 1.2631x over previous
//
#include <hip/hip_runtime.h>
#include <hip/hip_bf16.h>

#define NN 50000
#define EE 800000

typedef unsigned short u16;
typedef unsigned int u32;
typedef float f32x16 __attribute__((ext_vector_type(16)));
typedef short bf16x8_t __attribute__((ext_vector_type(8)));

__device__ __forceinline__ float bfu2f(u16 b) { return __builtin_bit_cast(float, ((u32)b) << 16); }
__device__ __forceinline__ float lo16(u32 d) { return __builtin_bit_cast(float, d << 16); }
__device__ __forceinline__ float hi16(u32 d) { return __builtin_bit_cast(float, d & 0xffff0000u); }
__device__ __forceinline__ u16 f2bfu(float f) {
    u32 u = __builtin_bit_cast(u32, f);
    u32 r = (u + 0x7fffu + ((u >> 16) & 1u)) >> 16;
    return (u16)r;
}
__device__ __forceinline__ u32 cvt_pk_bf16(float lo, float hi) {
    u32 r;
    asm("v_cvt_pk_bf16_f32 %0, %1, %2" : "=v"(r) : "v"(lo), "v"(hi));
    return r;
}

// ---------------------------------------------------------------------------
// k_wprep: transpose weights for MFMA B-fragments (once per launch).
//   wscT[part]: [u][w][v] bf16  (B[k=v][col=w] per u-slice, b128 per lane)
//   w1T:        [w][u]    bf16
// ---------------------------------------------------------------------------
__global__ __launch_bounds__(256) void k_wprep(
    const float* __restrict__ Wscs, const float* __restrict__ Wscv,
    const float* __restrict__ W1s, const float* __restrict__ W1v,
    u16* __restrict__ wscsT, u16* __restrict__ wscvT,
    u16* __restrict__ w1sT, u16* __restrict__ w1vT)
{
    int i = blockIdx.x * 256 + threadIdx.x;
    if (i < 16384) {
        int u = i >> 9, v = (i >> 5) & 15, w = i & 31;
        wscsT[(u * 32 + w) * 16 + v] = f2bfu(Wscs[i]);
        wscvT[(u * 32 + w) * 16 + v] = f2bfu(Wscv[i]);
    }
    if (i < 1024) {
        int u = i >> 5, w = i & 31;
        w1sT[w * 32 + u] = f2bfu(W1s[i]);
        w1vT[w * 32 + u] = f2bfu(W1v[i]);
    }
}

// ---------------------------------------------------------------------------
// k1_mfma: one wave per 32-node tile.
//  sc   = P(outer(h,x)) @ WscT   : 4 parts x 32 u-slices of mfma 32x32x16
//  h_s/v= h @ W1                 : 4 parts x 2 k-slices
// LDS: h tile as pair-packed [c/2][n][2] bf16 (8KB) -> broadcast reads.
// ---------------------------------------------------------------------------
__global__ __launch_bounds__(64) void k1_mfma(
    const float* __restrict__ x, const float* __restrict__ h,
    const u16* __restrict__ wscsT, const u16* __restrict__ wscvT,
    const u16* __restrict__ w1sT, const u16* __restrict__ w1vT,
    u16* __restrict__ hsv, float* __restrict__ out)
{
    __shared__ __align__(16) u16 sh[64 * 32 * 2];  // [cpair][node][half] 8KB
    u32* sh32 = (u32*)sh;
    const int l = threadIdx.x;
    const int base = blockIdx.x * 32;
    const int n = l & 31;   // A row (node in tile) == B col (w) per lane
    const int hi = l >> 5;  // k-half

    // stage h tile: lane reads row base+(l>>1), cols (l&1)*64..+63
    {
        int r = base + (l >> 1);
        if (r >= NN) r = NN - 1;
        const float* hp = h + (size_t)r * 128 + (l & 1) * 64;
        int nn = l >> 1;
        int cp0 = (l & 1) * 32;
#pragma unroll
        for (int q = 0; q < 16; q++) {
            float4 f = *(const float4*)(hp + q * 4);
            sh32[(cp0 + 2 * q + 0) * 32 + nn] = cvt_pk_bf16(f.x, f.y);
            sh32[(cp0 + 2 * q + 1) * 32 + nn] = cvt_pk_bf16(f.z, f.w);
        }
    }
    float xv0, xv1, xv2, xv3, xv4, xv5, xv6, xv7;
    {
        int r = base + n;
        if (r >= NN) r = NN - 1;
        const float* xp = x + (size_t)r * 16 + hi * 8;
        float4 a = *(const float4*)xp;
        float4 b = *(const float4*)(xp + 4);
        xv0 = a.x; xv1 = a.y; xv2 = a.z; xv3 = a.w;
        xv4 = b.x; xv5 = b.y; xv6 = b.z; xv7 = b.w;
    }
    __syncthreads();

    f32x16 accS, accX, accY, accZ;
#pragma unroll
    for (int i = 0; i < 16; i++) { accS[i] = 0.f; accX[i] = 0.f; accY[i] = 0.f; accZ[i] = 0.f; }

#define MK_A(A, s)                                                     \
    { union { u32 w[4]; bf16x8_t v; } t_;                              \
      t_.w[0] = cvt_pk_bf16((s) * xv0, (s) * xv1);                     \
      t_.w[1] = cvt_pk_bf16((s) * xv2, (s) * xv3);                     \
      t_.w[2] = cvt_pk_bf16((s) * xv4, (s) * xv5);                     \
      t_.w[3] = cvt_pk_bf16((s) * xv6, (s) * xv7);                     \
      A = t_.v; }

    const size_t boff = (size_t)n * 16 + hi * 8;
    bf16x8_t Bs = *(const bf16x8_t*)(wscsT + boff);
    bf16x8_t Bv = *(const bf16x8_t*)(wscvT + boff);
#pragma unroll 2
    for (int u = 0; u < 32; u++) {
        bf16x8_t BsN, BvN;
        if (u < 31) {
            BsN = *(const bf16x8_t*)(wscsT + (size_t)(u + 1) * 512 + boff);
            BvN = *(const bf16x8_t*)(wscvT + (size_t)(u + 1) * 512 + boff);
        }
        float hsu = bfu2f(sh[(u >> 1) * 64 + n * 2 + (u & 1)]);
        int c = 32 + 3 * u;
        float hx = bfu2f(sh[(c >> 1) * 64 + n * 2 + (c & 1)]);
        float hy = bfu2f(sh[((c + 1) >> 1) * 64 + n * 2 + ((c + 1) & 1)]);
        float hz = bfu2f(sh[((c + 2) >> 1) * 64 + n * 2 + ((c + 2) & 1)]);
        bf16x8_t A;
        MK_A(A, hsu); accS = __builtin_amdgcn_mfma_f32_32x32x16_bf16(A, Bs, accS, 0, 0, 0);
        MK_A(A, hx);  accX = __builtin_amdgcn_mfma_f32_32x32x16_bf16(A, Bv, accX, 0, 0, 0);
        MK_A(A, hy);  accY = __builtin_amdgcn_mfma_f32_32x32x16_bf16(A, Bv, accY, 0, 0, 0);
        MK_A(A, hz);  accZ = __builtin_amdgcn_mfma_f32_32x32x16_bf16(A, Bv, accZ, 0, 0, 0);
        Bs = BsN; Bv = BvN;
    }
#undef MK_A

    // sc epilogue: D col = n(lane&31) as w; row = node-in-tile via verified map
    const float inv_sc = 0.04419417382415922f;  // 1/sqrt(512)
#pragma unroll
    for (int r = 0; r < 16; r++) {
        int node2 = base + ((r & 3) + 8 * (r >> 2) + 4 * hi);
        if (node2 < NN) {
            float* op = out + (size_t)node2 * 128;
            op[n] = accS[r] * inv_sc;
            op[32 + n * 3 + 0] = accX[r] * inv_sc;
            op[32 + n * 3 + 1] = accY[r] * inv_sc;
            op[32 + n * 3 + 2] = accZ[r] * inv_sc;
        }
    }

    // W1 path: hs = h_s0 @ W1s, hv = h_v0 @ W1v (per m), K=32 = 2 slices
    const float inv_m = 0.17677669529663687f;  // 1/sqrt(32)
    {
        f32x16 aw;
#pragma unroll
        for (int i = 0; i < 16; i++) aw[i] = 0.f;
#pragma unroll
        for (int k0 = 0; k0 < 2; k0++) {
            union { u32 w[4]; bf16x8_t v; } A;
#pragma unroll
            for (int q = 0; q < 4; q++)
                A.w[q] = sh32[(8 * k0 + 4 * hi + q) * 32 + n];
            bf16x8_t B = *(const bf16x8_t*)(w1sT + n * 32 + 16 * k0 + 8 * hi);
            aw = __builtin_amdgcn_mfma_f32_32x32x16_bf16(A.v, B, aw, 0, 0, 0);
        }
#pragma unroll
        for (int r = 0; r < 16; r++) {
            int node2 = base + ((r & 3) + 8 * (r >> 2) + 4 * hi);
            if (node2 < NN) hsv[(size_t)node2 * 128 + n] = f2bfu(aw[r] * inv_m);
        }
    }
#pragma unroll
    for (int m = 0; m < 3; m++) {
        f32x16 aw;
#pragma unroll
        for (int i = 0; i < 16; i++) aw[i] = 0.f;
#pragma unroll
        for (int k0 = 0; k0 < 2; k0++) {
            union { u32 w[4]; bf16x8_t v; } A;
#pragma unroll
            for (int j = 0; j < 8; j += 2) {
                int u0 = 16 * k0 + 8 * hi + j;
                int c0 = 32 + 3 * u0 + m, c1 = c0 + 3;
                u16 a = sh[(c0 >> 1) * 64 + n * 2 + (c0 & 1)];
                u16 b = sh[(c1 >> 1) * 64 + n * 2 + (c1 & 1)];
                A.w[j >> 1] = (u32)a | ((u32)b << 16);
            }
            bf16x8_t B = *(const bf16x8_t*)(w1vT + n * 32 + 16 * k0 + 8 * hi);
            aw = __builtin_amdgcn_mfma_f32_32x32x16_bf16(A.v, B, aw, 0, 0, 0);
        }
#pragma unroll
        for (int r = 0; r < 16; r++) {
            int node2 = base + ((r & 3) + 8 * (r >> 2) + 4 * hi);
            if (node2 < NN) hsv[(size_t)node2 * 128 + 32 + n * 3 + m] = f2bfu(aw[r] * inv_m);
        }
    }
}

// ---------------------------------------------------------------------------
// CSR build: histogram -> scan. (scatter fused into k2a) — unchanged
// ---------------------------------------------------------------------------
__global__ __launch_bounds__(256) void k_hist(const int* __restrict__ eidx, int* __restrict__ deg) {
    int e = blockIdx.x * 256 + threadIdx.x;
    if (e < EE) atomicAdd(&deg[eidx[e]], 1);
}

__global__ __launch_bounds__(1024) void k_scan(const int* __restrict__ deg, int* __restrict__ row_ptr) {
    __shared__ int part[1024];
    const int t = threadIdx.x;
    const int base = t * 49;
    int s = 0;
#pragma unroll 7
    for (int i = 0; i < 49; i++) { int idx = base + i; if (idx < NN) s += deg[idx]; }
    part[t] = s;
    __syncthreads();
    for (int off = 1; off < 1024; off <<= 1) {
        int v = (t >= off) ? part[t - off] : 0;
        __syncthreads();
        part[t] += v;
        __syncthreads();
    }
    int run = (t > 0) ? part[t - 1] : 0;
    for (int i = 0; i < 49; i++) {
        int idx = base + i;
        if (idx < NN) { row_ptr[idx] = run; run += deg[idx]; }
    }
    if (t == 1023) row_ptr[NN] = run;
}

// ---------------------------------------------------------------------------
// K2a: streaming per-edge MLP front-half + scatter into CSR slots — unchanged
// ---------------------------------------------------------------------------
__global__ __launch_bounds__(256) void k2a_edge(
    const float* __restrict__ emb, const float* __restrict__ esh,
    const int* __restrict__ eidx, const float* __restrict__ fc1,
    const int* __restrict__ row_ptr, int* __restrict__ cursor,
    u32* __restrict__ edata)
{
    __shared__ float sfc1[64];
    const int tid = threadIdx.x;
    if (tid < 64) sfc1[tid] = fc1[tid];
    __syncthreads();
    int e = blockIdx.x * 256 + tid;
    if (e >= EE) return;
    const float invb = 0.3535533905932738f;
    float4 ea = *(const float4*)(emb + (size_t)e * 8);
    float4 eb = *(const float4*)(emb + (size_t)e * 8 + 4);
    float em[8] = {ea.x, ea.y, ea.z, ea.w, eb.x, eb.y, eb.z, eb.w};
    float z[8];
#pragma unroll
    for (int k = 0; k < 8; k++) {
        float t = 0.f;
#pragma unroll
        for (int j = 0; j < 8; j++) t += em[j] * sfc1[j * 8 + k];
        t *= invb;
        z[k] = t / (1.f + __expf(-t));
    }
    float4 sh = *(const float4*)(esh + (size_t)e * 4);
    int dst = eidx[e], src = eidx[EE + e];
    int p = atomicAdd(&cursor[dst], 1);
    size_t slot = (size_t)row_ptr[dst] + p;
    u32* wp = edata + slot * 8;
    uint4 A, B;
    A.x = (u32)f2bfu(z[0]) | ((u32)f2bfu(z[1]) << 16);
    A.y = (u32)f2bfu(z[2]) | ((u32)f2bfu(z[3]) << 16);
    A.z = (u32)f2bfu(z[4]) | ((u32)f2bfu(z[5]) << 16);
    A.w = (u32)f2bfu(z[6]) | ((u32)f2bfu(z[7]) << 16);
    B.x = (u32)f2bfu(sh.x) | ((u32)f2bfu(sh.y) << 16);
    B.y = (u32)f2bfu(sh.z) | ((u32)f2bfu(sh.w) << 16);
    B.z = (u32)src;
    B.w = 0;
    *(uint4*)wp = A;
    *(uint4*)(wp + 4) = B;
}

// ---------------------------------------------------------------------------
// K2b: gather + aggregate + fused output transform — unchanged
// ---------------------------------------------------------------------------
__device__ __forceinline__ void edge_body(
    const u32* __restrict__ r, const u16* __restrict__ hsv,
    const float* fcs, const float* fcv, int lane, int u, float inv3,
    float& acc_s, float& av0, float& av1, float& av2)
{
    uint4 A = *(const uint4*)r;
    uint4 B = *(const uint4*)(r + 4);
    float ws_ = lo16(A.x) * fcs[0] + hi16(A.x) * fcs[1] + lo16(A.y) * fcs[2] + hi16(A.y) * fcs[3]
              + lo16(A.z) * fcs[4] + hi16(A.z) * fcs[5] + lo16(A.w) * fcs[6] + hi16(A.w) * fcs[7];
    float wv_ = lo16(A.x) * fcv[0] + hi16(A.x) * fcv[1] + lo16(A.y) * fcv[2] + hi16(A.y) * fcv[3]
              + lo16(A.z) * fcv[4] + hi16(A.z) * fcv[5] + lo16(A.w) * fcv[6] + hi16(A.w) * fcv[7];
    float sh0 = lo16(B.x), s1x = hi16(B.x), s1y = lo16(B.y), s1z = hi16(B.y);
    const u16* hp = hsv + (size_t)(int)B.z * 128;
    if (lane < 32) {
        float hsvv = bfu2f(hp[u]);
        acc_s += hsvv * sh0 * ws_;
        av0 += hsvv * s1x * wv_; av1 += hsvv * s1y * wv_; av2 += hsvv * s1z * wv_;
    } else {
        const u16* q = hp + 32 + u * 3;
        float h0 = bfu2f(q[0]), h1 = bfu2f(q[1]), h2 = bfu2f(q[2]);
        acc_s += (h0 * s1x + h1 * s1y + h2 * s1z) * ws_ * inv3;
        av0 += h0 * sh0 * wv_; av1 += h1 * sh0 * wv_; av2 += h2 * sh0 * wv_;
    }
}

__global__ __launch_bounds__(256) void k2b_gather(
    const u32* __restrict__ edata, const float* __restrict__ fc2,
    const u16* __restrict__ hsv, const int* __restrict__ row_ptr,
    const float* __restrict__ W2s, const float* __restrict__ W2v,
    float* __restrict__ out)
{
    __shared__ float sW2s[2048];
    __shared__ float sW2v[2048];
    __shared__ float sred[4][256];
    const int tid = threadIdx.x;
    for (int i = tid; i < 2048; i += 256) { sW2s[i] = W2s[i]; sW2v[i] = W2v[i]; }

    const int wv = tid >> 6, lane = tid & 63;
    const int n = blockIdx.x * 4 + wv;
    const int beg = __builtin_amdgcn_readfirstlane(row_ptr[n]);
    const int end = __builtin_amdgcn_readfirstlane(row_ptr[n + 1]);

    const float invb = 0.3535533905932738f;
    const float inv3 = 0.5773502691896258f;
    const int u = lane & 31;
    const int cs = (lane < 32) ? lane : (96 + u);
    const int cv = (lane < 32) ? (32 + u) : (64 + u);
    float fcs[8], fcv[8];
#pragma unroll
    for (int j = 0; j < 8; j++) {
        fcs[j] = fc2[j * 128 + cs] * invb;
        fcv[j] = fc2[j * 128 + cv] * invb;
    }

    float a_s0 = 0.f, a00 = 0.f, a01 = 0.f, a02 = 0.f;
    float a_s1 = 0.f, a10 = 0.f, a11 = 0.f, a12 = 0.f;
    int s = beg;
    for (; s + 1 < end; s += 2) {
        edge_body(edata + (size_t)s * 8, hsv, fcs, fcv, lane, u, inv3, a_s0, a00, a01, a02);
        edge_body(edata + (size_t)(s + 1) * 8, hsv, fcs, fcv, lane, u, inv3, a_s1, a10, a11, a12);
    }
    if (s < end)
        edge_body(edata + (size_t)s * 8, hsv, fcs, fcv, lane, u, inv3, a_s0, a00, a01, a02);
    float acc_s = a_s0 + a_s1, av0 = a00 + a10, av1 = a01 + a11, av2 = a02 + a12;

    float* red = sred[wv];
    red[lane] = acc_s;
    red[64 + lane * 3 + 0] = av0;
    red[64 + lane * 3 + 1] = av1;
    red[64 + lane * 3 + 2] = av2;
    __syncthreads();

    const float sc2 = 0.03125f;
    if (lane < 32) {
        float acc = 0.f;
#pragma unroll 8
        for (int c = 0; c < 64; c++) acc += red[c] * sW2s[c * 32 + lane];
        size_t o = (size_t)n * 128 + lane;
        out[o] += acc * sc2;
    } else {
        const int w = lane - 32;
        float a0 = 0.f, a1 = 0.f, a2 = 0.f;
#pragma unroll 4
        for (int c = 0; c < 64; c++) {
            float wt = sW2v[c * 32 + w];
            a0 += red[64 + c * 3 + 0] * wt;
            a1 += red[64 + c * 3 + 1] * wt;
            a2 += red[64 + c * 3 + 2] * wt;
        }
        size_t o = (size_t)n * 128 + 32 + (size_t)w * 3;
        out[o + 0] += a0 * sc2;
        out[o + 1] += a1 * sc2;
        out[o + 2] += a2 * sc2;
    }
}

extern "C" void kernel_launch(void* const* d_in, const int* in_sizes, int n_in,
                              void* d_out, int out_size, void* d_ws, size_t ws_size,
                              hipStream_t stream) {
    const float* x    = (const float*)d_in[0];
    const float* h    = (const float*)d_in[1];
    const float* emb  = (const float*)d_in[2];
    const float* esh  = (const float*)d_in[3];
    const int*   eidx = (const int*)d_in[4];
    const float* W1s  = (const float*)d_in[5];
    const float* W1v  = (const float*)d_in[6];
    const float* fc1  = (const float*)d_in[7];
    const float* fc2  = (const float*)d_in[8];
    const float* Wscs = (const float*)d_in[9];
    const float* Wscv = (const float*)d_in[10];
    const float* W2s  = (const float*)d_in[11];
    const float* W2v  = (const float*)d_in[12];
    float* out = (float*)d_out;

    // ws: deg[NN] | row_ptr[NN+1] | cursor[NN] | edata u32[EE*8] | hsv u16[NN*128]
    //     | wscsT u16[16384] | wscvT u16[16384] | w1sT u16[1024] | w1vT u16[1024]
    int* deg      = (int*)d_ws;
    int* row_ptr  = deg + NN;
    int* cursor   = row_ptr + (NN + 1);
    u32* edata    = (u32*)(cursor + NN);
    u16* hsv      = (u16*)(edata + (size_t)EE * 8);
    u16* wscsT    = hsv + (size_t)NN * 128;
    u16* wscvT    = wscsT + 16384;
    u16* w1sT     = wscvT + 16384;
    u16* w1vT     = w1sT + 1024;

    hipMemsetAsync(d_ws, 0, (size_t)(NN + NN + 1 + NN) * 4, stream);
    k_wprep<<<64, 256, 0, stream>>>(Wscs, Wscv, W1s, W1v, wscsT, wscvT, w1sT, w1vT);
    k_hist<<<(EE + 255) / 256, 256, 0, stream>>>(eidx, deg);
    k_scan<<<1, 1024, 0, stream>>>(deg, row_ptr);
    k2a_edge<<<(EE + 255) / 256, 256, 0, stream>>>(emb, esh, eidx, fc1, row_ptr, cursor, edata);
    k1_mfma<<<(NN + 31) / 32, 64, 0, stream>>>(x, h, wscsT, wscvT, w1sT, w1vT, hsv, out);
    k2b_gather<<<NN / 4, 256, 0, stream>>>(edata, fc2, hsv, row_ptr, W2s, W2v, out);
}